// Round 2
// baseline (142.302 us; speedup 1.0000x reference)
//
#include <hip/hip_runtime.h>

// ConvT3d(32->16,k3,s2,p1)+BN+4^3 avgpool, bf16 MFMA, 4096-block grid.
// R7: staging latency fix. R6's 5-pass {load->pack->write} loop exposed 5
// serialized HBM round-trips per block. Now: issue ALL 40 loads/thread first
// (f[5][8] in flight, vmcnt<=63), then pack+write. f[] lifetime ends before
// acc init, so unified-file peak stays ~124 <= 128 at (256,4).
// kh-outer B-phasing (3 B-frags live), cvt_pk staging pack (R6).
// x-halo LDS layout [dihi][g][iw][o] (g=ci>>3,o=ci&7) unchanged.
// Parity decomposition (validated R1-R6): even o: k=1,i=o/2;
//   odd o=2m+1: k=0 -> i=m+1 ; k=2 -> i=m.
// kh-pair table: kh0: (hi1,oh1),(hi2,oh3); kh1: (hi0,oh0),(hi1,oh2);
//                kh2: (hi0,oh1),(hi1,oh3)

typedef __attribute__((ext_vector_type(8))) short bf16x8;
typedef __attribute__((ext_vector_type(4))) float f32x4;

static __device__ __forceinline__ unsigned short f2bf(float f) {
    unsigned int u = __float_as_uint(f);
    u = (u + 0x7fffu + ((u >> 16) & 1u)) >> 16;   // RNE
    return (unsigned short)u;
}
// RNE pack of 2 f32 -> 2 bf16 in one instr (identical rounding to f2bf)
static __device__ __forceinline__ unsigned cvtpk(float a, float b) {
    unsigned r;
    asm("v_cvt_pk_bf16_f32 %0, %1, %2" : "=v"(r) : "v"(a), "v"(b));
    return r;
}

// ---- w convert: w[ci][co][tap] fp32 -> wT[tap][co][ci] bf16 (tap=kd*9+kh*3+kw)
__global__ __launch_bounds__(256)
void kw(const float* __restrict__ w, unsigned short* __restrict__ wT)
{
    const int idx = blockIdx.x * 256 + threadIdx.x;
    if (idx < 13824) {
        const int ci = idx & 31, co = (idx >> 5) & 15, tap = idx >> 9;
        wT[idx] = f2bf(w[(ci * 16 + co) * 27 + tap]);
    }
}

// ---- fused stage + convT + BN-stats + pool partials
__global__ __launch_bounds__(256, 4)
void convf2(const float* __restrict__ x,
            const unsigned short* __restrict__ wT,
            const float* __restrict__ bias,
            float* __restrict__ pooled,
            float* __restrict__ psum, float* __restrict__ psq)
{
    const int ht = blockIdx.x, dt = blockIdx.y, n = blockIdx.z;
    const int tid = threadIdx.x;
    const int v = tid >> 6, lane = tid & 63;
    const int t = v & 1, odp = v >> 1;          // ow 16-tile, od pair
    const int c = lane & 15, qd = lane >> 4;    // co / A-row m, K-granule

    // xs[dihi(9)][g(4)][iw(33)][o(8)] bf16 -> 9*1056 shorts = 19008 B
    __shared__ unsigned short xs[9504];
    __shared__ float sred[4][16], qred[4][16], pbuf[2][8][16];

    // ---- stage x: issue ALL loads first (40/thread outstanding), then pack.
    // thread = (plane-half, g, iw); wave-uniform dihi per pass.
    const int iw = tid & 31, g = (tid >> 5) & 3, half = tid >> 7;
    float f[5][8];
    #pragma unroll
    for (int p = 0; p < 5; ++p) {
        const int dihi = p * 2 + half;
        const int di = dihi / 3, hi = dihi - di * 3;
        const int id = 2*dt + di, ih = 2*ht + hi;
        const bool ok = (dihi < 9) && (id < 32) && (ih < 32);
        const float* px = x + ((((n*32 + g*8)*32 + id)*32 + ih)*32) + iw;
        #pragma unroll
        for (int j = 0; j < 8; ++j)
            f[p][j] = ok ? px[j * 32768] : 0.f;
    }
    #pragma unroll
    for (int p = 0; p < 5; ++p) {
        const int dihi = p * 2 + half;
        if (dihi < 9) {
            uint4 u;
            u.x = cvtpk(f[p][0], f[p][1]); u.y = cvtpk(f[p][2], f[p][3]);
            u.z = cvtpk(f[p][4], f[p][5]); u.w = cvtpk(f[p][6], f[p][7]);
            *(uint4*)(xs + dihi*1056 + g*264 + iw*8) = u;
        }
    }
    if (tid < 36) {
        const int dihi = tid >> 2, gg = tid & 3;
        *(uint4*)(xs + dihi*1056 + gg*264 + 256) = make_uint4(0,0,0,0);
    }

    __syncthreads();

    f32x4 acc[2][4][2];   // [ol][oh][par]
    #pragma unroll
    for (int ol = 0; ol < 2; ++ol)
        #pragma unroll
        for (int oh = 0; oh < 4; ++oh)
            #pragma unroll
            for (int par = 0; par < 2; ++par)
                acc[ol][oh][par] = (f32x4){0.f,0.f,0.f,0.f};

    const int iwb = 16 * t + c;
    auto LDA = [&](int dihi, int sofs) -> bf16x8 {
        return *(const bf16x8*)(xs + dihi*1056 + qd*264 + (iwb + sofs)*8);
    };
    auto LDB = [&](int tap) -> bf16x8 {
        return *(const bf16x8*)(wT + tap * 512 + c * 32 + qd * 8);
    };

    // kh-outer pair table: [kh][pair] -> (hi, oh). Only 3 B-frags live.
    constexpr int KHP[3][2][2] = {
        {{1,1},{2,3}},   // kh0
        {{0,0},{1,2}},   // kh1
        {{0,1},{1,3}},   // kh2
    };

    auto PH = [&](int ol, int base, int di) {
        #pragma unroll
        for (int kh = 0; kh < 3; ++kh) {
            const bf16x8 B0 = LDB(base + kh*3 + 0);
            const bf16x8 B1 = LDB(base + kh*3 + 1);
            const bf16x8 B2 = LDB(base + kh*3 + 2);
            #pragma unroll
            for (int p = 0; p < 2; ++p) {
                const int hi = KHP[kh][p][0], oh = KHP[kh][p][1];
                const bf16x8 A0 = LDA(di*3 + hi, 0), A1 = LDA(di*3 + hi, 1);
                acc[ol][oh][0] = __builtin_amdgcn_mfma_f32_16x16x32_bf16(
                    A0, B1, acc[ol][oh][0], 0, 0, 0);
                acc[ol][oh][1] = __builtin_amdgcn_mfma_f32_16x16x32_bf16(
                    A1, B0, acc[ol][oh][1], 0, 0, 0);
                acc[ol][oh][1] = __builtin_amdgcn_mfma_f32_16x16x32_bf16(
                    A0, B2, acc[ol][oh][1], 0, 0, 0);
            }
        }
    };

    PH(0,  9, odp);       // kd=1 -> ol0
    PH(1, 18, odp);       // kd=2 -> ol1
    PH(1,  0, odp + 1);   // kd=0 -> ol1

    // ---- epilogue: bias, BN stats (masked), pool partials (validated R2-R6)
    const float bv = bias[c];
    float s = 0.f, sq = 0.f;
    float P[2] = {0.f, 0.f};
    #pragma unroll
    for (int ol = 0; ol < 2; ++ol) {
        const int odg = 2*odp + ol;
        const bool odok = !(dt == 15 && odg == 3);
        #pragma unroll
        for (int oh = 0; oh < 4; ++oh) {
            const bool ohok = !(ht == 15 && oh == 3);
            #pragma unroll
            for (int par = 0; par < 2; ++par)
                #pragma unroll
                for (int r = 0; r < 4; ++r) {
                    const float val = acc[ol][oh][par][r] + bv;
                    const bool owok = !(par == 1 && t == 1 && qd == 3 && r == 3);
                    const float mk = (odok && ohok && owok) ? 1.f : 0.f;
                    s += mk * val; sq += mk * val * val;
                    P[r >> 1] += val;
                }
        }
    }
    s  += __shfl_xor(s, 16, 64);  s  += __shfl_xor(s, 32, 64);
    sq += __shfl_xor(sq, 16, 64); sq += __shfl_xor(sq, 32, 64);

    if (lane < 16) { sred[v][lane] = s; qred[v][lane] = sq; }
    if (odp == 0 && dt < 15 && ht < 15) {
        pbuf[t][2*qd + 0][c] = P[0];
        pbuf[t][2*qd + 1][c] = P[1];
    }
    __syncthreads();
    if (tid < 16) {
        const int blk = (n*16 + dt)*16 + ht;
        psum[tid*4096 + blk] = sred[0][tid]+sred[1][tid]+sred[2][tid]+sred[3][tid];
        psq [tid*4096 + blk] = qred[0][tid]+qred[1][tid]+qred[2][tid]+qred[3][tid];
    }
    if (odp == 1 && dt < 15 && ht < 15) {
        #pragma unroll
        for (int jj = 0; jj < 2; ++jj) {
            const int jl = 2*qd + jj, jg = 8*t + jl;
            if (jg < 15) {
                const float tot = pbuf[t][jl][c] + P[jj];
                pooled[(n*16 + c)*3375 + dt*225 + ht*15 + jg] = tot * (1.f/64.f);
            }
        }
    }
}

__global__ void bnfinal(const float* __restrict__ psum, const float* __restrict__ psq,
                        const float* __restrict__ gamma, const float* __restrict__ beta,
                        float* __restrict__ bn)
{
    const int co = blockIdx.x;
    const int t  = threadIdx.x;
    float S = 0, Q = 0;
    for (int blk = t; blk < 4096; blk += 256) {
        S += psum[co*4096 + blk];
        Q += psq [co*4096 + blk];
    }
    #pragma unroll
    for (int off = 32; off > 0; off >>= 1) {
        S += __shfl_down(S, off, 64);
        Q += __shfl_down(Q, off, 64);
    }
    __shared__ float rs[4], rq[4];
    if ((t & 63) == 0) { rs[t >> 6] = S; rq[t >> 6] = Q; }
    __syncthreads();
    if (t == 0) {
        S = rs[0] + rs[1] + rs[2] + rs[3];
        Q = rq[0] + rq[1] + rq[2] + rq[3];
        const float cnt = 16.f * 63.f * 63.f * 63.f;
        const float mean = S / cnt;
        const float var  = Q / cnt - mean * mean;
        const float inv  = rsqrtf(var + 1e-5f);
        const float sc   = inv * gamma[co];
        bn[co]      = sc;
        bn[16 + co] = beta[co] - mean * sc;
    }
}

__global__ void finalize(const float* __restrict__ pooled, const float* __restrict__ bn,
                         float* __restrict__ out)
{
    const int i  = blockIdx.x * 256 + threadIdx.x;   // 864000 = 3375*256
    const int co = (i / 3375) & 15;
    out[i] = pooled[i] * bn[co] + bn[16 + co];
}

extern "C" void kernel_launch(void* const* d_in, const int* in_sizes, int n_in,
                              void* d_out, int out_size, void* d_ws, size_t ws_size,
                              hipStream_t stream)
{
    const float* x     = (const float*)d_in[0];
    const float* w     = (const float*)d_in[1];
    const float* b     = (const float*)d_in[2];
    const float* gamma = (const float*)d_in[3];
    const float* beta  = (const float*)d_in[4];
    float* out = (float*)d_out;

    char* wsb = (char*)d_ws;
    unsigned short* wT = (unsigned short*)wsb;        // 27,648 B
    float* pooled = (float*)(wsb + 27648);            // 3,456,000 B
    float* psum   = (float*)(wsb + 27648 + 3456000);  // 262,144 B
    float* psq    = (float*)(wsb + 27648 + 3456000 + 262144);
    float* bn     = (float*)(wsb + 27648 + 3456000 + 2*262144);

    kw<<<54, 256, 0, stream>>>(w, wT);
    dim3 grid(16, 16, 16);   // (ht, dt, n)
    convf2<<<grid, 256, 0, stream>>>(x, wT, b, pooled, psum, psq);
    bnfinal<<<16, 256, 0, stream>>>(psum, psq, gamma, beta, bn);
    finalize<<<3375, 256, 0, stream>>>(pooled, bn, out);
}

// Round 3
// 137.176 us; speedup vs baseline: 1.0374x; 1.0374x over previous
//
#include <hip/hip_runtime.h>

// ConvT3d(32->16,k3,s2,p1)+BN+4^3 avgpool, bf16 MFMA, 4096-block grid.
// R8: latency fix INSIDE the 128-reg budget (R7 failed because 40 scalar
// loads can't be in flight under launch_bounds(256,4) -> compiler
// re-serialized; VGPR stayed 60).
//  (a) staging: 9 x float4 wide loads along iw (36 VGPR, one round-trip,
//      16B/lane coalesced) + in-register 4iw x 8ci transpose
//      (cvt_pk -> shfl_xor8+v_perm half-swap -> shfl_xor16+select) ->
//      ds_write_b64 into the SAME validated xs[dihi][g][iw][o] layout.
//  (b) B pipeline: 9 flattened (phase,kh) groups, prefetch group s+1's
//      3 B-frags (6 live = 24 VGPR) while MFMAing group s.
// Parity decomposition (validated R1-R7): even o: k=1,i=o/2;
//   odd o=2m+1: k=0 -> i=m+1 ; k=2 -> i=m.
// kh-pair table: kh0: (hi1,oh1),(hi2,oh3); kh1: (hi0,oh0),(hi1,oh2);
//                kh2: (hi0,oh1),(hi1,oh3)

typedef __attribute__((ext_vector_type(8))) short bf16x8;
typedef __attribute__((ext_vector_type(4))) float f32x4;

static __device__ __forceinline__ unsigned short f2bf(float f) {
    unsigned int u = __float_as_uint(f);
    u = (u + 0x7fffu + ((u >> 16) & 1u)) >> 16;   // RNE
    return (unsigned short)u;
}
// RNE pack of 2 f32 -> 2 bf16 in one instr (identical rounding to f2bf)
static __device__ __forceinline__ unsigned cvtpk(float a, float b) {
    unsigned r;
    asm("v_cvt_pk_bf16_f32 %0, %1, %2" : "=v"(r) : "v"(a), "v"(b));
    return r;
}

// ---- w convert: w[ci][co][tap] fp32 -> wT[tap][co][ci] bf16 (tap=kd*9+kh*3+kw)
__global__ __launch_bounds__(256)
void kw(const float* __restrict__ w, unsigned short* __restrict__ wT)
{
    const int idx = blockIdx.x * 256 + threadIdx.x;
    if (idx < 13824) {
        const int ci = idx & 31, co = (idx >> 5) & 15, tap = idx >> 9;
        wT[idx] = f2bf(w[(ci * 16 + co) * 27 + tap]);
    }
}

// ---- fused stage + convT + BN-stats + pool partials
__global__ __launch_bounds__(256, 4)
void convf2(const float* __restrict__ x,
            const unsigned short* __restrict__ wT,
            const float* __restrict__ bias,
            float* __restrict__ pooled,
            float* __restrict__ psum, float* __restrict__ psq)
{
    const int ht = blockIdx.x, dt = blockIdx.y, n = blockIdx.z;
    const int tid = threadIdx.x;
    const int v = tid >> 6, lane = tid & 63;
    const int t = v & 1, odp = v >> 1;          // ow 16-tile, od pair
    const int c = lane & 15, qd = lane >> 4;    // co / A-row m, K-granule

    // xs[dihi(9)][g(4)][iw(33)][o(8)] bf16 -> 9*1056 shorts = 19008 B
    __shared__ unsigned short xs[9504];
    __shared__ float sred[4][16], qred[4][16], pbuf[2][8][16];

    const float bv = bias[c];   // hoisted: hides epilogue load latency

    // ---- stage x: wide loads. thread = (ci = tid>>3, iw-quad q = tid&7).
    // Wave v holds ci-octet g=v. 9 x float4 issued back-to-back (1 round-trip).
    const int ciS = tid >> 3, q = tid & 7;
    const int oL = ciS & 7;                     // = lane bits 3..5
    const float* xbase = x + (n*32 + ciS)*32768 + 4*q;
    float4 F[9];
    #pragma unroll
    for (int p = 0; p < 9; ++p) {
        const int di = p / 3, hi = p - 3*(p/3);
        const int id = 2*dt + di, ih = 2*ht + hi;
        const bool ok = (id < 32) && (ih < 32);   // block-uniform
        F[p] = ok ? *(const float4*)(xbase + id*1024 + ih*32)
                  : make_float4(0.f, 0.f, 0.f, 0.f);
    }
    // in-register transpose 4iw x 8ci -> [iw][o] packs, per plane:
    //  round A (lane^8, 16-bit half <-> iw bit0) via v_perm
    //  round B (lane^16, reg <-> iw bit1) via select
    // lane(oL,q) ends with o' = [4h,4h+4) at iw = 4q + (oL&3), h = oL>>2.
    const unsigned selP = (lane & 8) ? 0x07060302u : 0x01000504u;
    const int iwT = 4*q + (oL & 3), hT = oL >> 2;
    #pragma unroll
    for (int p = 0; p < 9; ++p) {
        unsigned u0 = cvtpk(F[p].x, F[p].y);
        unsigned u1 = cvtpk(F[p].z, F[p].w);
        const unsigned a0 = (unsigned)__shfl_xor((int)u0, 8, 64);
        const unsigned a1 = (unsigned)__shfl_xor((int)u1, 8, 64);
        u0 = __builtin_amdgcn_perm(u0, a0, selP);
        u1 = __builtin_amdgcn_perm(u1, a1, selP);
        const unsigned t0 = (unsigned)__shfl_xor((int)u0, 16, 64);
        const unsigned t1 = (unsigned)__shfl_xor((int)u1, 16, 64);
        const unsigned n0 = (lane & 16) ? t1 : u0;
        const unsigned n1 = (lane & 16) ? u1 : t0;
        *(uint2*)(xs + p*1056 + v*264 + iwT*8 + 4*hT) = make_uint2(n0, n1);
    }
    if (tid < 36) {
        const int dihi = tid >> 2, gg = tid & 3;
        *(uint4*)(xs + dihi*1056 + gg*264 + 256) = make_uint4(0,0,0,0);
    }

    __syncthreads();

    f32x4 acc[2][4][2];   // [ol][oh][par]
    #pragma unroll
    for (int ol = 0; ol < 2; ++ol)
        #pragma unroll
        for (int oh = 0; oh < 4; ++oh)
            #pragma unroll
            for (int par = 0; par < 2; ++par)
                acc[ol][oh][par] = (f32x4){0.f,0.f,0.f,0.f};

    const int iwb = 16 * t + c;
    auto LDA = [&](int dihi, int sofs) -> bf16x8 {
        return *(const bf16x8*)(xs + dihi*1056 + qd*264 + (iwb + sofs)*8);
    };
    auto LDB = [&](int tap) -> bf16x8 {
        return *(const bf16x8*)(wT + tap * 512 + c * 32 + qd * 8);
    };

    // kh-outer pair table: [kh][pair] -> (hi, oh)
    constexpr int KHP[3][2][2] = {
        {{1,1},{2,3}},   // kh0
        {{0,0},{1,2}},   // kh1
        {{0,1},{1,3}},   // kh2
    };
    const int PB[3]  = {9, 18, 0};       // tap base per phase (kd=1,2,0)
    const int POL[3] = {0, 1, 1};        // ol per phase
    const int PDI[3] = {odp, odp, odp + 1};

    bf16x8 B0 = LDB(9 + 0), B1 = LDB(9 + 1), B2 = LDB(9 + 2);
    #pragma unroll
    for (int s = 0; s < 9; ++s) {
        const int ph = s / 3, kh = s - 3*(s/3);
        bf16x8 N0, N1, N2;
        if (s < 8) {                      // prefetch next kh-group
            const int sn = s + 1;
            const int phn = sn / 3, khn = sn - 3*(sn/3);
            const int bn_ = PB[phn] + khn * 3;
            N0 = LDB(bn_ + 0); N1 = LDB(bn_ + 1); N2 = LDB(bn_ + 2);
        }
        const int ol = POL[ph], di = PDI[ph];
        #pragma unroll
        for (int pp = 0; pp < 2; ++pp) {
            const int hi = KHP[kh][pp][0], oh = KHP[kh][pp][1];
            const bf16x8 A0 = LDA(di*3 + hi, 0), A1 = LDA(di*3 + hi, 1);
            acc[ol][oh][0] = __builtin_amdgcn_mfma_f32_16x16x32_bf16(
                A0, B1, acc[ol][oh][0], 0, 0, 0);
            acc[ol][oh][1] = __builtin_amdgcn_mfma_f32_16x16x32_bf16(
                A1, B0, acc[ol][oh][1], 0, 0, 0);
            acc[ol][oh][1] = __builtin_amdgcn_mfma_f32_16x16x32_bf16(
                A0, B2, acc[ol][oh][1], 0, 0, 0);
        }
        if (s < 8) { B0 = N0; B1 = N1; B2 = N2; }
    }

    // ---- epilogue: bias, BN stats (masked), pool partials (validated R2-R7)
    float s = 0.f, sq = 0.f;
    float P[2] = {0.f, 0.f};
    #pragma unroll
    for (int ol = 0; ol < 2; ++ol) {
        const int odg = 2*odp + ol;
        const bool odok = !(dt == 15 && odg == 3);
        #pragma unroll
        for (int oh = 0; oh < 4; ++oh) {
            const bool ohok = !(ht == 15 && oh == 3);
            #pragma unroll
            for (int par = 0; par < 2; ++par)
                #pragma unroll
                for (int r = 0; r < 4; ++r) {
                    const float val = acc[ol][oh][par][r] + bv;
                    const bool owok = !(par == 1 && t == 1 && qd == 3 && r == 3);
                    const float mk = (odok && ohok && owok) ? 1.f : 0.f;
                    s += mk * val; sq += mk * val * val;
                    P[r >> 1] += val;
                }
        }
    }
    s  += __shfl_xor(s, 16, 64);  s  += __shfl_xor(s, 32, 64);
    sq += __shfl_xor(sq, 16, 64); sq += __shfl_xor(sq, 32, 64);

    if (lane < 16) { sred[v][lane] = s; qred[v][lane] = sq; }
    if (odp == 0 && dt < 15 && ht < 15) {
        pbuf[t][2*qd + 0][c] = P[0];
        pbuf[t][2*qd + 1][c] = P[1];
    }
    __syncthreads();
    if (tid < 16) {
        const int blk = (n*16 + dt)*16 + ht;
        psum[tid*4096 + blk] = sred[0][tid]+sred[1][tid]+sred[2][tid]+sred[3][tid];
        psq [tid*4096 + blk] = qred[0][tid]+qred[1][tid]+qred[2][tid]+qred[3][tid];
    }
    if (odp == 1 && dt < 15 && ht < 15) {
        #pragma unroll
        for (int jj = 0; jj < 2; ++jj) {
            const int jl = 2*qd + jj, jg = 8*t + jl;
            if (jg < 15) {
                const float tot = pbuf[t][jl][c] + P[jj];
                pooled[(n*16 + c)*3375 + dt*225 + ht*15 + jg] = tot * (1.f/64.f);
            }
        }
    }
}

__global__ void bnfinal(const float* __restrict__ psum, const float* __restrict__ psq,
                        const float* __restrict__ gamma, const float* __restrict__ beta,
                        float* __restrict__ bn)
{
    const int co = blockIdx.x;
    const int t  = threadIdx.x;
    float S = 0, Q = 0;
    for (int blk = t; blk < 4096; blk += 256) {
        S += psum[co*4096 + blk];
        Q += psq [co*4096 + blk];
    }
    #pragma unroll
    for (int off = 32; off > 0; off >>= 1) {
        S += __shfl_down(S, off, 64);
        Q += __shfl_down(Q, off, 64);
    }
    __shared__ float rs[4], rq[4];
    if ((t & 63) == 0) { rs[t >> 6] = S; rq[t >> 6] = Q; }
    __syncthreads();
    if (t == 0) {
        S = rs[0] + rs[1] + rs[2] + rs[3];
        Q = rq[0] + rq[1] + rq[2] + rq[3];
        const float cnt = 16.f * 63.f * 63.f * 63.f;
        const float mean = S / cnt;
        const float var  = Q / cnt - mean * mean;
        const float inv  = rsqrtf(var + 1e-5f);
        const float sc   = inv * gamma[co];
        bn[co]      = sc;
        bn[16 + co] = beta[co] - mean * sc;
    }
}

__global__ void finalize(const float* __restrict__ pooled, const float* __restrict__ bn,
                         float* __restrict__ out)
{
    const int i  = blockIdx.x * 256 + threadIdx.x;   // 864000 = 3375*256
    const int co = (i / 3375) & 15;
    out[i] = pooled[i] * bn[co] + bn[16 + co];
}

extern "C" void kernel_launch(void* const* d_in, const int* in_sizes, int n_in,
                              void* d_out, int out_size, void* d_ws, size_t ws_size,
                              hipStream_t stream)
{
    const float* x     = (const float*)d_in[0];
    const float* w     = (const float*)d_in[1];
    const float* b     = (const float*)d_in[2];
    const float* gamma = (const float*)d_in[3];
    const float* beta  = (const float*)d_in[4];
    float* out = (float*)d_out;

    char* wsb = (char*)d_ws;
    unsigned short* wT = (unsigned short*)wsb;        // 27,648 B
    float* pooled = (float*)(wsb + 27648);            // 3,456,000 B
    float* psum   = (float*)(wsb + 27648 + 3456000);  // 262,144 B
    float* psq    = (float*)(wsb + 27648 + 3456000 + 262144);
    float* bn     = (float*)(wsb + 27648 + 3456000 + 2*262144);

    kw<<<54, 256, 0, stream>>>(w, wT);
    dim3 grid(16, 16, 16);   // (ht, dt, n)
    convf2<<<grid, 256, 0, stream>>>(x, wT, b, pooled, psum, psq);
    bnfinal<<<16, 256, 0, stream>>>(psum, psq, gamma, beta, bn);
    finalize<<<3375, 256, 0, stream>>>(pooled, bn, out);
}